// Round 1
// baseline (396.668 us; speedup 1.0000x reference)
//
#include <hip/hip_runtime.h>
#include <hip/hip_bf16.h>

// SpatialFrequencyLoss: sum_s w_s * mean( (conv(in, LoG_s) - conv(tgt, LoG_s))^2 )
// = sum_s w_s * mean( conv(in - tgt, LoG_s)^2 )            [linearity]
// LoG_s[i,j] = c*(U(i)G(j) + G(i)U(j)) - m                 [rank-3 separable]
//   c = 1/(2*pi*ss^2), U(x)=(x^2-ss)exp(-x^2/2ss), G(x)=exp(-x^2/2ss),
//   m = 2c*sum(U)*sum(G)/k^2  (the mean-subtraction constant -> box filter)

#define HH 512
#define WW 512
#define NC 12                      // 4*3 images
#define NPIX (NC * HH * WW)        // 3,145,728

static const int   KS_H[6]   = {5, 11, 21, 39, 77, 155};
static const int   KOFF_H[6] = {0, 5, 16, 37, 76, 153};   // prefix sums, total 308
static const float WSFL_H[6] = {600.f, 500.f, 400.f, 20.f, 10.f, 10.f};

__constant__ int   d_KS[6]   = {5, 11, 21, 39, 77, 155};
__constant__ int   d_KOFF[6] = {0, 5, 16, 37, 76, 153};
__constant__ float d_SIG[6]  = {0.6f, 1.2f, 2.4f, 4.8f, 9.6f, 19.2f};

// ---------------------------------------------------------------------------
// Init: compute 1D coefficient tables U, G per sigma, constants c and m,
// and zero the output accumulator. One block, runs in a few microseconds.
// ---------------------------------------------------------------------------
__global__ void init_kernel(float* __restrict__ cU, float* __restrict__ cG,
                            float* __restrict__ sc, float* __restrict__ out) {
    __shared__ float rU[256], rG[256];
    const int tid = threadIdx.x;
    if (tid == 0) out[0] = 0.f;
    for (int s = 0; s < 6; ++s) {
        const int   k   = d_KS[s];
        const int   off = d_KOFF[s];
        const int   p   = k / 2;
        const float ss  = d_SIG[s] * d_SIG[s];
        float su = 0.f, sg = 0.f;
        for (int j = tid; j < k; j += 256) {
            const float x = (float)(j - p);
            const float g = expf(-x * x / (2.f * ss));
            const float u = (x * x - ss) * g;
            cU[off + j] = u;
            cG[off + j] = g;
            su += u; sg += g;
        }
        rU[tid] = su; rG[tid] = sg;
        __syncthreads();
        for (int d = 128; d > 0; d >>= 1) {
            if (tid < d) { rU[tid] += rU[tid + d]; rG[tid] += rG[tid + d]; }
            __syncthreads();
        }
        if (tid == 0) {
            const float PI = 3.14159265358979323846f;
            const float c  = 1.f / (2.f * PI * ss * ss);
            const float m  = 2.f * c * rU[0] * rG[0] / ((float)k * (float)k);
            sc[2 * s]     = c;
            sc[2 * s + 1] = m;
        }
        __syncthreads();
    }
}

__device__ __forceinline__ int refl(int i, int n) {
    return i < 0 ? -i : (i >= n ? 2 * n - 2 - i : i);
}

// ---------------------------------------------------------------------------
// Horizontal pass: one block per row (NC*H rows). Stage diff row (+halo, with
// reflect) in LDS; each thread produces 4 adjacent columns of HU = d*U,
// HG = d*G, HB = d*box via float4 sliding-window reads from LDS.
// ---------------------------------------------------------------------------
template <int K>
__global__ __launch_bounds__(128) void hconv(
    const float* __restrict__ inp, const float* __restrict__ tgt,
    float4* __restrict__ hu, float4* __restrict__ hg, float4* __restrict__ hb,
    const float* __restrict__ cU, const float* __restrict__ cG) {
    constexpr int P  = K / 2;
    constexpr int NT = K + 3;             // taps each thread touches (4 outputs)
    constexpr int NQ = (NT + 3) / 4;      // float4 chunks
    constexpr int SD = 512 + 4 * NQ;      // LDS floats (padded past W+K-1)
    __shared__ __align__(16) float sd[SD];

    const int tid = threadIdx.x;
    const int row = blockIdx.x;           // [0, NC*H)
    const int rb  = row * WW;

    for (int x = tid; x < WW + K - 1; x += 128) {
        const int cix = refl(x - P, WW);
        sd[x] = inp[rb + cix] - tgt[rb + cix];
    }
    __syncthreads();

    float au[4] = {0, 0, 0, 0}, ag[4] = {0, 0, 0, 0}, ab[4] = {0, 0, 0, 0};
    const float4* sd4 = (const float4*)sd;
#pragma unroll
    for (int q = 0; q < NQ; ++q) {
        const float4 v4 = sd4[tid + q];
        const float vv[4] = {v4.x, v4.y, v4.z, v4.w};
#pragma unroll
        for (int dt = 0; dt < 4; ++dt) {
            const int t = 4 * q + dt;
            if (t < NT) {
                const float v = vv[dt];
#pragma unroll
                for (int rr = 0; rr < 4; ++rr) {
                    const int j = t - rr;      // compile-time after unroll
                    if (j >= 0 && j < K) {
                        au[rr] = fmaf(v, cU[j], au[rr]);
                        ag[rr] = fmaf(v, cG[j], ag[rr]);
                        ab[rr] += v;
                    }
                }
            }
        }
    }
    const int o4 = row * (WW / 4) + tid;
    hu[o4] = make_float4(au[0], au[1], au[2], au[3]);
    hg[o4] = make_float4(ag[0], ag[1], ag[2], ag[3]);
    hb[o4] = make_float4(ab[0], ab[1], ab[2], ab[3]);
}

// ---------------------------------------------------------------------------
// Vertical pass + squared-loss reduction. Each thread owns one column slice of
// R=16 output rows: register sliding window cuts plane reads ~16x. Applies
// o = c*(su+sg) - m*sb, accumulates w*o^2/NPIX, block-reduce, one atomicAdd.
// ---------------------------------------------------------------------------
template <int K>
__global__ __launch_bounds__(256) void vconv(
    const float* __restrict__ hu, const float* __restrict__ hg,
    const float* __restrict__ hb, const float* __restrict__ cU,
    const float* __restrict__ cG, const float* __restrict__ sc,
    float* __restrict__ out, float scale) {
    constexpr int R = 16, P = K / 2;
    const int tid = threadIdx.x;
    const int bid = blockIdx.x;
    const int img = bid >> 6;                 // 64 blocks per image
    const int rem = bid & 63;
    const int h0  = (rem >> 1) * R;
    const int w   = ((rem & 1) << 8) + tid;
    const int base = img * (HH * WW) + w;
    const float c = sc[0], m = sc[1];

    float su[R], sg[R], sb[R];
#pragma unroll
    for (int rr = 0; rr < R; ++rr) { su[rr] = 0.f; sg[rr] = 0.f; sb[rr] = 0.f; }

    auto addr = [&](int t) {
        const int r = refl(h0 - P + t, HH);
        return base + r * WW;
    };
    auto pred_step = [&](int t) {
        const int idx = addr(t);
        const float gu = hu[idx], gg = hg[idx], gb = hb[idx];
#pragma unroll
        for (int rr = 0; rr < R; ++rr) {
            const int  j  = t - rr;
            const bool v  = (j >= 0) && (j < K);
            const int  jc = v ? j : 0;
            const float uu = v ? cU[jc] : 0.f;
            const float gc = v ? cG[jc] : 0.f;
            su[rr] = fmaf(gg, uu, su[rr]);
            sg[rr] = fmaf(gu, gc, sg[rr]);
            sb[rr] += v ? gb : 0.f;
        }
    };

    if constexpr (K >= R) {
        for (int t = 0; t < R - 1; ++t) pred_step(t);
#pragma unroll 2
        for (int t = R - 1; t < K; ++t) {     // all R outputs valid: no predicates
            const int idx = addr(t);
            const float gu = hu[idx], gg = hg[idx], gb = hb[idx];
#pragma unroll
            for (int rr = 0; rr < R; ++rr) {
                const int j = t - rr;          // uniform runtime index -> s_load
                su[rr] = fmaf(gg, cU[j], su[rr]);
                sg[rr] = fmaf(gu, cG[j], sg[rr]);
                sb[rr] += gb;
            }
        }
        for (int t = K; t < K + R - 1; ++t) pred_step(t);
    } else {
        for (int t = 0; t < K + R - 1; ++t) pred_step(t);
    }

    float lsum = 0.f;
#pragma unroll
    for (int rr = 0; rr < R; ++rr) {
        const float o = c * (su[rr] + sg[rr]) - m * sb[rr];
        lsum = fmaf(o, o, lsum);
    }
    lsum *= scale;

#pragma unroll
    for (int off = 32; off > 0; off >>= 1) lsum += __shfl_down(lsum, off);
    __shared__ float red[4];
    const int lane = tid & 63, wid = tid >> 6;
    if (lane == 0) red[wid] = lsum;
    __syncthreads();
    if (tid == 0) atomicAdd(out, red[0] + red[1] + red[2] + red[3]);
}

// ---------------------------------------------------------------------------
extern "C" void kernel_launch(void* const* d_in, const int* in_sizes, int n_in,
                              void* d_out, int out_size, void* d_ws, size_t ws_size,
                              hipStream_t stream) {
    (void)in_sizes; (void)n_in; (void)out_size; (void)ws_size;
    const float* inp = (const float*)d_in[0];
    const float* tgt = (const float*)d_in[1];
    float* out = (float*)d_out;
    float* ws  = (float*)d_ws;

    float* hu = ws;                         // NPIX floats
    float* hg = ws + (size_t)NPIX;          // NPIX floats
    float* hb = ws + 2 * (size_t)NPIX;      // NPIX floats
    float* cU = ws + 3 * (size_t)NPIX;      // 308 floats
    float* cG = cU + 308;                   // 308 floats
    float* sc = cG + 308;                   // 12 floats (c, m per sigma)

    init_kernel<<<dim3(1), dim3(256), 0, stream>>>(cU, cG, sc, out);

#define RUN_SIGMA(S, KK)                                                          \
    hconv<KK><<<dim3(NC * HH), dim3(128), 0, stream>>>(                           \
        inp, tgt, (float4*)hu, (float4*)hg, (float4*)hb,                          \
        cU + KOFF_H[S], cG + KOFF_H[S]);                                          \
    vconv<KK><<<dim3(NC * (HH / 16) * 2), dim3(256), 0, stream>>>(                \
        hu, hg, hb, cU + KOFF_H[S], cG + KOFF_H[S], sc + 2 * (S), out,            \
        WSFL_H[S] / (float)NPIX);

    RUN_SIGMA(0, 5)
    RUN_SIGMA(1, 11)
    RUN_SIGMA(2, 21)
    RUN_SIGMA(3, 39)
    RUN_SIGMA(4, 77)
    RUN_SIGMA(5, 155)
#undef RUN_SIGMA
}